// Round 16
// baseline (45.491 us; speedup 1.0000x reference)
//
#include <hip/hip_runtime.h>
#include <math.h>

#define DM1 63
#define VSTR 68            // LDS row stride for v-vectors

typedef float f4 __attribute__((ext_vector_type(4)));

// d_ws float offsets
#define OFF_WRO 0u                          // shifted W_t*ro: 512*64
#define SZ_WRO  (512u*64u)
#define OFF_WTH (OFF_WRO + SZ_WRO)          // shifted W_t*th1: 1024*64
#define SZ_WTH  (1024u*64u)
#define OFF_TC  (OFF_WTH + SZ_WTH)          // per-b consts {th0,nrm,q,bhu}: 1024*4
#define SZ_TC   (1024u*4u)
#define OFF_ZK  (OFF_TC + SZ_TC)            // per-r consts {zeta,kk,v2,-}: 512*4

__device__ __forceinline__ float qreduce(float d) {   // 4-lane quad sum
    int t = __builtin_amdgcn_mov_dpp(__float_as_int(d), 0xB1, 0xF, 0xF, true);
    d += __int_as_float(t);
    t = __builtin_amdgcn_mov_dpp(__float_as_int(d), 0x4E, 0xF, 0xF, true);
    d += __int_as_float(t);
    return d;
}

// 16-lane all-lanes sum (quad xor1, xor2, row_ror:4, row_ror:8) — all-DPP,
// validated in rounds 11-12.
__device__ __forceinline__ float red16(float d) {
    d += __int_as_float(__builtin_amdgcn_mov_dpp(__float_as_int(d), 0xB1,  0xF, 0xF, true));
    d += __int_as_float(__builtin_amdgcn_mov_dpp(__float_as_int(d), 0x4E,  0xF, 0xF, true));
    d += __int_as_float(__builtin_amdgcn_mov_dpp(__float_as_int(d), 0x124, 0xF, 0xF, true));
    d += __int_as_float(__builtin_amdgcn_mov_dpp(__float_as_int(d), 0x128, 0xF, 0xF, true));
    return d;
}

// 64-lane sum via DPP row_shr/row_bcast ladder; uniform result via readlane(63).
__device__ __forceinline__ float wred(float x) {
    float s = x;
#define ST(ctrl, rmask) s += __int_as_float(__builtin_amdgcn_update_dpp( \
        0, __float_as_int(s), ctrl, rmask, 0xF, true))
    ST(0x111, 0xF);   // row_shr:1
    ST(0x112, 0xF);   // row_shr:2
    ST(0x114, 0xF);   // row_shr:4
    ST(0x118, 0xF);   // row_shr:8
    ST(0x142, 0xA);   // row_bcast:15 -> rows 1,3
    ST(0x143, 0xC);   // row_bcast:31 -> rows 2,3
#undef ST
    return __int_as_float(__builtin_amdgcn_readlane(__float_as_int(s), 63));
}

// ---------------- K_prep: one block per relation, 512 threads (8 waves).
// gelu both sides into LDS, then matrix-vector Householder applications only.
__global__ __launch_bounds__(512) void k_prep(const float* __restrict__ rwh,
                                              const float* __restrict__ rwt,
                                              const float* __restrict__ bwh,
                                              const float* __restrict__ bwt,
                                              const int* __restrict__ pos,
                                              const float* __restrict__ emb,
                                              const float* __restrict__ bh,
                                              float* __restrict__ wrog,
                                              float* __restrict__ wthg,
                                              float* __restrict__ thcg,
                                              float* __restrict__ zkg) {
    int r = blockIdx.x;                  // 0..511
    __shared__ __align__(16) float vvh[DM1 * VSTR];
    __shared__ __align__(16) float vvt[DM1 * VSTR];
    __shared__ float sch[64], sct[64];
    __shared__ float rovh_s[64], rovt_s[64];
    __shared__ float hcons[2];           // zeta_h, kz_h
    __shared__ int blist[64];
    __shared__ int bcnt;
    int tid = threadIdx.x;
    if (tid == 0) bcnt = 0;

    // gelu both sides
    const float* rwhr = rwh + (size_t)r * 3969;
    const float* rwtr = rwt + (size_t)r * 3969;
    for (int idx = tid; idx < 3969; idx += 512) {
        int s = idx / 63, j = idx - s * 63;
        float xh = rwhr[idx], xt = rwtr[idx];
        vvh[s * VSTR + j] = 0.5f * xh * (1.f + erff(xh * 0.70710678118654752f));
        vvt[s * VSTR + j] = 0.5f * xt * (1.f + erff(xt * 0.70710678118654752f));
    }
    if (tid < DM1) { vvh[tid * VSTR + 63] = 0.f; vvt[tid * VSTR + 63] = 0.f; }

    // boost vectors + consts (independent of vv)
    if (tid < 64) {
        int c = tid;
        float rov = (c < 63) ? tanhf(bwh[r * 63 + c]) * 0.015625f : 0.f;
        rovh_s[c] = rov;
        float p = rov * rov;
        #pragma unroll
        for (int off = 32; off; off >>= 1) p += __shfl_xor(p, off);
        if (c == 0) {
            float v2 = p;
            float zeta = 1.f / (sqrtf(1.f - v2) + 1e-8f);
            hcons[0] = zeta;
            hcons[1] = (zeta - 1.f) / (v2 + 1e-9f);
        }
    } else if (tid < 128) {
        int c = tid - 64;
        float rov = (c < 63) ? tanhf(bwt[r * 63 + c]) * 0.015625f : 0.f;
        rovt_s[c] = rov;
        float p = rov * rov;
        #pragma unroll
        for (int off = 32; off; off >>= 1) p += __shfl_xor(p, off);
        if (c == 0) {
            float v2 = p;
            float zeta = 1.f / (sqrtf(1.f - v2) + 1e-8f);
            zkg[r * 4]     = zeta;
            zkg[r * 4 + 1] = (zeta - 1.f) / (v2 + 1e-9f);
            zkg[r * 4 + 2] = v2;
        }
    }
    __syncthreads();

    // per-step scales sqrt(2/||v||^2), both sides; + scan pos for our b's
    if (tid < 252) {
        int s = tid >> 2, p = tid & 3;
        const float* vr = &vvh[s * VSTR + p * 16];
        float sum = 0.f;
        #pragma unroll
        for (int j = 0; j < 16; j++) { float v = vr[j]; sum = fmaf(v, v, sum); }
        sum = qreduce(sum);
        if (p == 0) sch[s] = sqrtf(2.f / sum);
        const float* vr2 = &vvt[s * VSTR + p * 16];
        float sum2 = 0.f;
        #pragma unroll
        for (int j = 0; j < 16; j++) { float v = vr2[j]; sum2 = fmaf(v, v, sum2); }
        sum2 = qreduce(sum2);
        if (p == 0) sct[s] = sqrtf(2.f / sum2);
    }
    for (int i = tid; i < 1024; i += 512)
        if (pos[3 * i + 1] == r) { int s = atomicAdd(&bcnt, 1); if (s < 64) blist[s] = i; }
    __syncthreads();

    for (int idx = tid; idx < DM1 * 64; idx += 512) {
        int s = idx >> 6, j = idx & 63;
        vvh[s * VSTR + j] *= sch[s];
        vvt[s * VSTR + j] *= sct[s];
    }
    __syncthreads();

    int lane = tid & 63, wv = tid >> 6;   // wv 0..7
    int cnt = bcnt < 64 ? bcnt : 64;
    float zeta_h = hcons[0], kz_h = hcons[1];

    if (wv == 0) {
        // wro = W_t * ro_t  (descending), one-ahead LDS prefetch
        float y = rovt_s[lane];
        float vs = vvt[62 * VSTR + lane];
        #pragma unroll 7
        for (int s = 62; s >= 0; s--) {
            float vn = (s > 0) ? vvt[(s - 1) * VSTR + lane] : 0.f;
            float dot = wred(y * vs);
            y = fmaf(-dot, vs, y);
            vs = vn;
        }
        if (lane < 63) wrog[r * 64 + 1 + lane] = y;
        else           wrog[r * 64] = 0.f;
    } else {
        for (int e = wv - 1; e < cnt; e += 7) {
            int b = blist[e];
            int u = pos[3 * b];
            const float* hrow = emb + (size_t)u * 64;
            float x0 = hrow[0];
            float y = (lane < 63) ? hrow[1 + lane] : 0.f;
            // xn = h1^T W_h : ascending
            float vs = vvh[0 * VSTR + lane];
            #pragma unroll 7
            for (int s = 0; s < 63; s++) {
                float vn = (s < 62) ? vvh[(s + 1) * VSTR + lane] : 0.f;
                float dot = wred(y * vs);
                y = fmaf(-dot, vs, y);
                vs = vn;
            }
            // boost head
            float rh = rovh_s[lane];
            float dot = wred(y * rh);
            float th1 = (lane < 63) ? fmaf(-zeta_h * x0, rh, y) + kz_h * rh * dot : 0.f;
            float th0 = zeta_h * x0 - zeta_h * dot;
            float nn = wred(th1 * th1);
            float qq = wred(th1 * rovt_s[lane]);
            if (lane == 0) {
                thcg[b * 4]     = th0;
                thcg[b * 4 + 1] = nn;
                thcg[b * 4 + 2] = qq;
                thcg[b * 4 + 3] = tanhf(bh[u]);
            }
            // wth = W_t * th1 : descending
            float z = th1;
            float ws2 = vvt[62 * VSTR + lane];
            #pragma unroll 7
            for (int s = 62; s >= 0; s--) {
                float wn = (s > 0) ? vvt[(s - 1) * VSTR + lane] : 0.f;
                float d2 = wred(z * ws2);
                z = fmaf(-d2, ws2, z);
                ws2 = wn;
            }
            if (lane < 63) wthg[b * 64 + 1 + lane] = z;
            else           wthg[b * 64] = 0.f;
        }
    }
}

// ---------------- K3: 16-lanes-per-row gather scoring. Each lane loads one
// 16B chunk; consecutive 4 lanes share one 64B cache line (TA request merge).
__global__ __launch_bounds__(256) void k3_score(
    const int* __restrict__ pos, const int* __restrict__ neg,
    const float* __restrict__ emb, const float* __restrict__ bt,
    const float* __restrict__ wrog, const float* __restrict__ wthg,
    const float* __restrict__ thcg, const float* __restrict__ zkg,
    float* __restrict__ out) {
    __shared__ __align__(16) float wro_s[64];
    __shared__ __align__(16) float wth_s[64];
    __shared__ float cst[7];

    int b = blockIdx.x, j = threadIdx.x;
    int r = pos[b * 3 + 1];

    if (j < 16)            ((f4*)wro_s)[j]      = ((const f4*)(wrog + r * 64))[j];
    else if (j < 32)       ((f4*)wth_s)[j - 16] = ((const f4*)(wthg + b * 64))[j - 16];
    else if (j == 32)      { cst[0] = zkg[r * 4]; cst[1] = zkg[r * 4 + 1]; cst[2] = zkg[r * 4 + 2]; }
    else if (j == 33)      { const float* tc = thcg + b * 4;
                             cst[3] = tc[0]; cst[4] = tc[1]; cst[5] = tc[2]; cst[6] = tc[3]; }
    __syncthreads();

    int c16 = j & 15, grp = j >> 4;      // 16 groups/block, lane c16 owns bytes [16*c16,16*c16+16)
    f4 wr = ((const f4*)wro_s)[c16];
    f4 wt = ((const f4*)wth_s)[c16];
    float zeta = cst[0], kk = cst[1], v2 = cst[2];
    float th0 = cst[3], nrm = cst[4], qd = cst[5], bhu = cst[6];

    #pragma unroll
    for (int cc = 0; cc < 16; cc++) {
        int cand = cc * 16 + grp;
        int v = (cand == 0) ? pos[b * 3 + 2] : neg[b * 255 + cand - 1];
        f4 tv = *((const f4*)(emb + (size_t)v * 64) + c16);
        float btv = bt[v];

        f4 p1 = tv * wr, p2 = tv * wt, p3 = tv * tv;
        float s1 = red16((p1[0] + p1[1]) + (p1[2] + p1[3]));
        float s2 = red16((p2[0] + p2[1]) + (p2[2] + p2[3]));
        float s3r = red16((p3[0] + p3[1]) + (p3[2] + p3[3]));
        float x0 = red16((c16 == 0) ? tv[0] : 0.f);
        float s3 = s3r - x0 * x0;

        float A  = fmaf(kk, s1, -zeta * x0);
        float d0 = fmaf(zeta, x0 - s1, -th0);
        float m1 = s3 + nrm - 2.f * s2 + A * (2.f * (s1 - qd) + A * v2);
        float mkv = m1 - d0 * d0;
        if (c16 == 0) out[b * 256 + cand] = 0.85f - mkv + bhu + tanhf(btv);
    }
}

extern "C" void kernel_launch(void* const* d_in, const int* in_sizes, int n_in,
                              void* d_out, int out_size, void* d_ws, size_t ws_size,
                              hipStream_t stream) {
    const int*   pos = (const int*)d_in[0];
    const int*   neg = (const int*)d_in[1];
    const float* emb = (const float*)d_in[2];
    const float* bh  = (const float*)d_in[3];
    const float* bt  = (const float*)d_in[4];
    const float* rwh = (const float*)d_in[5];
    const float* bwh = (const float*)d_in[6];
    const float* rwt = (const float*)d_in[7];
    const float* bwt = (const float*)d_in[8];
    float* ws   = (float*)d_ws;
    float* wrog = ws + OFF_WRO;
    float* wthg = ws + OFF_WTH;
    float* thcg = ws + OFF_TC;
    float* zkg  = ws + OFF_ZK;
    float* out  = (float*)d_out;

    k_prep  <<<dim3(512),  dim3(512), 0, stream>>>(rwh, rwt, bwh, bwt, pos, emb,
                                                   bh, wrog, wthg, thcg, zkg);
    k3_score<<<dim3(1024), dim3(256), 0, stream>>>(pos, neg, emb, bt, wrog, wthg,
                                                   thcg, zkg, out);
}

// Round 17
// 43.237 us; speedup vs baseline: 1.0521x; 1.0521x over previous
//
#include <hip/hip_runtime.h>
#include <math.h>

#define DM1 63
#define VSTR 68            // LDS row stride for v-vectors

typedef float f4 __attribute__((ext_vector_type(4)));

// d_ws float offsets
#define OFF_WRO 0u                          // shifted W_t*ro: 512*64
#define SZ_WRO  (512u*64u)
#define OFF_WTH (OFF_WRO + SZ_WRO)          // shifted W_t*th1: 1024*64
#define SZ_WTH  (1024u*64u)
#define OFF_TC  (OFF_WTH + SZ_WTH)          // per-b consts {th0,nrm,q,bhu}: 1024*4
#define SZ_TC   (1024u*4u)
#define OFF_ZK  (OFF_TC + SZ_TC)            // per-r consts {zeta,kk,v2,-}: 512*4

__device__ __forceinline__ float qreduce(float d) {   // 4-lane quad sum
    int t = __builtin_amdgcn_mov_dpp(__float_as_int(d), 0xB1, 0xF, 0xF, true);
    d += __int_as_float(t);
    t = __builtin_amdgcn_mov_dpp(__float_as_int(d), 0x4E, 0xF, 0xF, true);
    d += __int_as_float(t);
    return d;
}

__device__ __forceinline__ float qbcast0(float x) {   // broadcast lane 4k -> quad
    return __int_as_float(__builtin_amdgcn_mov_dpp(__float_as_int(x), 0x00, 0xF, 0xF, true));
}

// 16-lane all-lanes sum within each DPP row (quad xor1, xor2, row_ror:4,
// row_ror:8) — validated rounds 11-12. Reduces each 16-lane group separately.
__device__ __forceinline__ float red16(float d) {
    d += __int_as_float(__builtin_amdgcn_mov_dpp(__float_as_int(d), 0xB1,  0xF, 0xF, true));
    d += __int_as_float(__builtin_amdgcn_mov_dpp(__float_as_int(d), 0x4E,  0xF, 0xF, true));
    d += __int_as_float(__builtin_amdgcn_mov_dpp(__float_as_int(d), 0x124, 0xF, 0xF, true));
    d += __int_as_float(__builtin_amdgcn_mov_dpp(__float_as_int(d), 0x128, 0xF, 0xF, true));
    return d;
}

__device__ __forceinline__ float dot4(f4 a, f4 b) {
    f4 p = a * b;
    return (p[0] + p[1]) + (p[2] + p[3]);
}

// ---------------- K_prep: one block per relation, 512 threads (8 waves).
// Chains are 16-lane-parallel (f4 per lane): 4 independent chains per wave,
// 32 chain slots per block -> wro + all entries in one pass.
__global__ __launch_bounds__(512) void k_prep(const float* __restrict__ rwh,
                                              const float* __restrict__ rwt,
                                              const float* __restrict__ bwh,
                                              const float* __restrict__ bwt,
                                              const int* __restrict__ pos,
                                              const float* __restrict__ emb,
                                              const float* __restrict__ bh,
                                              float* __restrict__ wrog,
                                              float* __restrict__ wthg,
                                              float* __restrict__ thcg,
                                              float* __restrict__ zkg) {
    int r = blockIdx.x;                  // 0..511
    __shared__ __align__(16) float vvh[DM1 * VSTR];
    __shared__ __align__(16) float vvt[DM1 * VSTR];
    __shared__ float sch[64], sct[64];
    __shared__ __align__(16) float rovh_s[64], rovt_s[64];
    __shared__ float hcons[2];           // zeta_h, kz_h
    __shared__ int blist[64];
    __shared__ int bcnt;
    int tid = threadIdx.x;
    if (tid == 0) bcnt = 0;

    // gelu both sides
    const float* rwhr = rwh + (size_t)r * 3969;
    const float* rwtr = rwt + (size_t)r * 3969;
    for (int idx = tid; idx < 3969; idx += 512) {
        int s = idx / 63, j = idx - s * 63;
        float xh = rwhr[idx], xt = rwtr[idx];
        vvh[s * VSTR + j] = 0.5f * xh * (1.f + erff(xh * 0.70710678118654752f));
        vvt[s * VSTR + j] = 0.5f * xt * (1.f + erff(xt * 0.70710678118654752f));
    }
    if (tid < DM1) { vvh[tid * VSTR + 63] = 0.f; vvt[tid * VSTR + 63] = 0.f; }

    // boost vectors + consts
    if (tid < 64) {
        int c = tid;
        float rov = (c < 63) ? tanhf(bwh[r * 63 + c]) * 0.015625f : 0.f;
        rovh_s[c] = rov;
        float p = rov * rov;
        #pragma unroll
        for (int off = 32; off; off >>= 1) p += __shfl_xor(p, off);
        if (c == 0) {
            float v2 = p;
            float zeta = 1.f / (sqrtf(1.f - v2) + 1e-8f);
            hcons[0] = zeta;
            hcons[1] = (zeta - 1.f) / (v2 + 1e-9f);
        }
    } else if (tid < 128) {
        int c = tid - 64;
        float rov = (c < 63) ? tanhf(bwt[r * 63 + c]) * 0.015625f : 0.f;
        rovt_s[c] = rov;
        float p = rov * rov;
        #pragma unroll
        for (int off = 32; off; off >>= 1) p += __shfl_xor(p, off);
        if (c == 0) {
            float v2 = p;
            float zeta = 1.f / (sqrtf(1.f - v2) + 1e-8f);
            zkg[r * 4]     = zeta;
            zkg[r * 4 + 1] = (zeta - 1.f) / (v2 + 1e-9f);
            zkg[r * 4 + 2] = v2;
        }
    }
    __syncthreads();

    // per-step scales + scan pos for our b's
    if (tid < 252) {
        int s = tid >> 2, p = tid & 3;
        const float* vr = &vvh[s * VSTR + p * 16];
        float sum = 0.f;
        #pragma unroll
        for (int j = 0; j < 16; j++) { float v = vr[j]; sum = fmaf(v, v, sum); }
        sum = qreduce(sum);
        if (p == 0) sch[s] = sqrtf(2.f / sum);
        const float* vr2 = &vvt[s * VSTR + p * 16];
        float sum2 = 0.f;
        #pragma unroll
        for (int j = 0; j < 16; j++) { float v = vr2[j]; sum2 = fmaf(v, v, sum2); }
        sum2 = qreduce(sum2);
        if (p == 0) sct[s] = sqrtf(2.f / sum2);
    }
    for (int i = tid; i < 1024; i += 512)
        if (pos[3 * i + 1] == r) { int s = atomicAdd(&bcnt, 1); if (s < 64) blist[s] = i; }
    __syncthreads();

    for (int idx = tid; idx < DM1 * 64; idx += 512) {
        int s = idx >> 6, j = idx & 63;
        vvh[s * VSTR + j] *= sch[s];
        vvt[s * VSTR + j] *= sct[s];
    }
    __syncthreads();

    int lane = tid & 63, wv = tid >> 6;   // wv 0..7
    int g = lane >> 4, c = lane & 15;     // group g (4/wave), lane-part c
    int cnt = bcnt < 64 ? bcnt : 64;
    float zeta_h = hcons[0], kz_h = hcons[1];

    int rounds = (cnt + 30) / 31; if (rounds < 1) rounds = 1;
    for (int rd = 0; rd < rounds; rd++) {
        int gslot = wv * 4 + g;                       // 0..31
        bool iswro = (rd == 0) && (gslot == 0);
        int eslot = rd * 31 + gslot - 1;              // entry index
        bool isent = (gslot > 0) && (eslot < cnt);
        int bb = isent ? blist[eslot] : 0;
        int u  = pos[3 * bb];
        const float* hrow = emb + (size_t)u * 64;

        // init ascending y = h1 elems [4c..4c+4) (shifted-by-1 read via lane shfl)
        f4 a = ((const f4*)hrow)[c];
        float an0 = __shfl(a[0], lane + 1);
        f4 y;
        y[0] = a[1]; y[1] = a[2]; y[2] = a[3];
        y[3] = (c == 15) ? 0.f : an0;
        if (!isent) y = (f4)0.f;
        float x0 = hrow[0];

        // ascending chain through W_h
        #pragma unroll 7
        for (int s = 0; s < 63; s++) {
            f4 vs = *(const f4*)(&vvh[s * VSTR + 4 * c]);
            float dot = red16(dot4(y, vs));
            y -= dot * vs;
        }

        // boost head -> th1 (f4/lane), th0, consts
        f4 rh4 = ((const f4*)rovh_s)[c];
        f4 rt4 = ((const f4*)rovt_s)[c];
        float dot = red16(dot4(y, rh4));
        f4 th1 = y + (-zeta_h * x0) * rh4 + (kz_h * dot) * rh4;
        float th0 = zeta_h * x0 - zeta_h * dot;
        float nn = red16(dot4(th1, th1));
        float qq = red16(dot4(th1, rt4));
        if (isent && c == 0) {
            thcg[bb * 4]     = th0;
            thcg[bb * 4 + 1] = nn;
            thcg[bb * 4 + 2] = qq;
            thcg[bb * 4 + 3] = tanhf(bh[u]);
        }

        // descending chain through W_t: entries carry th1, wro carries ro_t
        f4 z = isent ? th1 : (iswro ? rt4 : (f4)0.f);
        #pragma unroll 7
        for (int s = 62; s >= 0; s--) {
            f4 vs = *(const f4*)(&vvt[s * VSTR + 4 * c]);
            float d2 = red16(dot4(z, vs));
            z -= d2 * vs;
        }

        if (isent) {
            float* wo = wthg + bb * 64;
            if (c == 0) wo[0] = 0.f;
            #pragma unroll
            for (int k = 0; k < 4; k++) {
                int idx = 4 * c + k;
                if (idx < 63) wo[1 + idx] = z[k];
            }
        } else if (iswro) {
            float* wo = wrog + r * 64;
            if (c == 0) wo[0] = 0.f;
            #pragma unroll
            for (int k = 0; k < 4; k++) {
                int idx = 4 * c + k;
                if (idx < 63) wo[1 + idx] = z[k];
            }
        }
    }
}

// ---------------- K3: quad-cooperative gather scoring (r15 form), 2048 blocks
// (128 cands each) for 1.5-2x resident waves.
__global__ __launch_bounds__(256, 6) void k3_score(
    const int* __restrict__ pos, const int* __restrict__ neg,
    const float* __restrict__ emb, const float* __restrict__ bt,
    const float* __restrict__ wrog, const float* __restrict__ wthg,
    const float* __restrict__ thcg, const float* __restrict__ zkg,
    float* __restrict__ out) {
    __shared__ __align__(16) float wro_s[64];
    __shared__ __align__(16) float wth_s[64];
    __shared__ float cst[7];

    int blk = blockIdx.x;
    int b = blk >> 1, half = blk & 1;
    int j = threadIdx.x;
    int r = pos[b * 3 + 1];
    int qslot = j >> 2, p = j & 3;

    if (j < 16)            ((f4*)wro_s)[j]      = ((const f4*)(wrog + r * 64))[j];
    else if (j < 32)       ((f4*)wth_s)[j - 16] = ((const f4*)(wthg + b * 64))[j - 16];
    else if (j == 32)      { cst[0] = zkg[r * 4]; cst[1] = zkg[r * 4 + 1]; cst[2] = zkg[r * 4 + 2]; }
    else if (j == 33)      { const float* tc = thcg + b * 4;
                             cst[3] = tc[0]; cst[4] = tc[1]; cst[5] = tc[2]; cst[6] = tc[3]; }
    __syncthreads();

    float zeta = cst[0], kk = cst[1], v2 = cst[2];
    float th0 = cst[3], nrm = cst[4], qd = cst[5], bhu = cst[6];
    const f4* wr4 = (const f4*)wro_s + p * 4;
    const f4* wt4 = (const f4*)wth_s + p * 4;

    #pragma unroll
    for (int cc = 0; cc < 2; cc++) {
        int cand = half * 128 + cc * 64 + qslot;
        int v = (cand == 0) ? pos[b * 3 + 2] : neg[b * 255 + cand - 1];
        const f4* tp = (const f4*)(emb + (size_t)v * 64) + p * 4;
        f4 t0 = tp[0], t1 = tp[1], t2 = tp[2], t3 = tp[3];
        float btv = bt[v];

        float x0 = qbcast0(t0[0]);                   // element 0 lives in lane p=0
        f4 a1 = t0 * wr4[0] + t1 * wr4[1] + t2 * wr4[2] + t3 * wr4[3];
        f4 a2 = t0 * wt4[0] + t1 * wt4[1] + t2 * wt4[2] + t3 * wt4[3];
        f4 a3 = t0 * t0 + t1 * t1 + t2 * t2 + t3 * t3;
        float s1 = qreduce((a1[0] + a1[1]) + (a1[2] + a1[3]));
        float s2 = qreduce((a2[0] + a2[1]) + (a2[2] + a2[3]));
        float s3 = qreduce((a3[0] + a3[1]) + (a3[2] + a3[3])) - x0 * x0;

        float A  = fmaf(kk, s1, -zeta * x0);
        float d0 = fmaf(zeta, x0 - s1, -th0);
        float m1 = s3 + nrm - 2.f * s2 + A * (2.f * (s1 - qd) + A * v2);
        float mkv = m1 - d0 * d0;
        if (p == 0) out[b * 256 + cand] = 0.85f - mkv + bhu + tanhf(btv);
    }
}

extern "C" void kernel_launch(void* const* d_in, const int* in_sizes, int n_in,
                              void* d_out, int out_size, void* d_ws, size_t ws_size,
                              hipStream_t stream) {
    const int*   pos = (const int*)d_in[0];
    const int*   neg = (const int*)d_in[1];
    const float* emb = (const float*)d_in[2];
    const float* bh  = (const float*)d_in[3];
    const float* bt  = (const float*)d_in[4];
    const float* rwh = (const float*)d_in[5];
    const float* bwh = (const float*)d_in[6];
    const float* rwt = (const float*)d_in[7];
    const float* bwt = (const float*)d_in[8];
    float* ws   = (float*)d_ws;
    float* wrog = ws + OFF_WRO;
    float* wthg = ws + OFF_WTH;
    float* thcg = ws + OFF_TC;
    float* zkg  = ws + OFF_ZK;
    float* out  = (float*)d_out;

    k_prep  <<<dim3(512),  dim3(512), 0, stream>>>(rwh, rwt, bwh, bwt, pos, emb,
                                                   bh, wrog, wthg, thcg, zkg);
    k3_score<<<dim3(2048), dim3(256), 0, stream>>>(pos, neg, emb, bt, wrog, wthg,
                                                   thcg, zkg, out);
}

// Round 18
// 42.538 us; speedup vs baseline: 1.0694x; 1.0164x over previous
//
#include <hip/hip_runtime.h>
#include <math.h>

#define DM1 63
#define VSTR 68            // LDS row stride for v-vectors

typedef float f4 __attribute__((ext_vector_type(4)));

// d_ws float offsets
#define OFF_WRO 0u                          // shifted W_t*ro: 512*64
#define SZ_WRO  (512u*64u)
#define OFF_WTH (OFF_WRO + SZ_WRO)          // shifted W_t*th1: 1024*64
#define SZ_WTH  (1024u*64u)
#define OFF_TC  (OFF_WTH + SZ_WTH)          // per-b consts {th0,nrm,q,bhu}: 1024*4
#define SZ_TC   (1024u*4u)
#define OFF_ZK  (OFF_TC + SZ_TC)            // per-r consts {zeta,kk,v2,-}: 512*4

__device__ __forceinline__ float qreduce(float d) {   // 4-lane quad sum
    int t = __builtin_amdgcn_mov_dpp(__float_as_int(d), 0xB1, 0xF, 0xF, true);
    d += __int_as_float(t);
    t = __builtin_amdgcn_mov_dpp(__float_as_int(d), 0x4E, 0xF, 0xF, true);
    d += __int_as_float(t);
    return d;
}

__device__ __forceinline__ float qbcast0(float x) {   // broadcast lane 4k -> quad
    return __int_as_float(__builtin_amdgcn_mov_dpp(__float_as_int(x), 0x00, 0xF, 0xF, true));
}

// 16-lane all-lanes sum within each DPP row (quad xor1, xor2, row_ror:4,
// row_ror:8) — validated rounds 11-17.
__device__ __forceinline__ float red16(float d) {
    d += __int_as_float(__builtin_amdgcn_mov_dpp(__float_as_int(d), 0xB1,  0xF, 0xF, true));
    d += __int_as_float(__builtin_amdgcn_mov_dpp(__float_as_int(d), 0x4E,  0xF, 0xF, true));
    d += __int_as_float(__builtin_amdgcn_mov_dpp(__float_as_int(d), 0x124, 0xF, 0xF, true));
    d += __int_as_float(__builtin_amdgcn_mov_dpp(__float_as_int(d), 0x128, 0xF, 0xF, true));
    return d;
}

__device__ __forceinline__ float dot4(f4 a, f4 b) {
    f4 p = a * b;
    return (p[0] + p[1]) + (p[2] + p[3]);
}

// ---------------- K_prep (r17 form): one block per relation, 512 threads.
// 16-lane-parallel chains (f4/lane), 32 chain slots -> wro + all entries one pass.
__global__ __launch_bounds__(512) void k_prep(const float* __restrict__ rwh,
                                              const float* __restrict__ rwt,
                                              const float* __restrict__ bwh,
                                              const float* __restrict__ bwt,
                                              const int* __restrict__ pos,
                                              const float* __restrict__ emb,
                                              const float* __restrict__ bh,
                                              float* __restrict__ wrog,
                                              float* __restrict__ wthg,
                                              float* __restrict__ thcg,
                                              float* __restrict__ zkg) {
    int r = blockIdx.x;                  // 0..511
    __shared__ __align__(16) float vvh[DM1 * VSTR];
    __shared__ __align__(16) float vvt[DM1 * VSTR];
    __shared__ float sch[64], sct[64];
    __shared__ __align__(16) float rovh_s[64], rovt_s[64];
    __shared__ float hcons[2];           // zeta_h, kz_h
    __shared__ int blist[64];
    __shared__ int bcnt;
    int tid = threadIdx.x;
    if (tid == 0) bcnt = 0;

    const float* rwhr = rwh + (size_t)r * 3969;
    const float* rwtr = rwt + (size_t)r * 3969;
    for (int idx = tid; idx < 3969; idx += 512) {
        int s = idx / 63, j = idx - s * 63;
        float xh = rwhr[idx], xt = rwtr[idx];
        vvh[s * VSTR + j] = 0.5f * xh * (1.f + erff(xh * 0.70710678118654752f));
        vvt[s * VSTR + j] = 0.5f * xt * (1.f + erff(xt * 0.70710678118654752f));
    }
    if (tid < DM1) { vvh[tid * VSTR + 63] = 0.f; vvt[tid * VSTR + 63] = 0.f; }

    if (tid < 64) {
        int c = tid;
        float rov = (c < 63) ? tanhf(bwh[r * 63 + c]) * 0.015625f : 0.f;
        rovh_s[c] = rov;
        float p = rov * rov;
        #pragma unroll
        for (int off = 32; off; off >>= 1) p += __shfl_xor(p, off);
        if (c == 0) {
            float v2 = p;
            float zeta = 1.f / (sqrtf(1.f - v2) + 1e-8f);
            hcons[0] = zeta;
            hcons[1] = (zeta - 1.f) / (v2 + 1e-9f);
        }
    } else if (tid < 128) {
        int c = tid - 64;
        float rov = (c < 63) ? tanhf(bwt[r * 63 + c]) * 0.015625f : 0.f;
        rovt_s[c] = rov;
        float p = rov * rov;
        #pragma unroll
        for (int off = 32; off; off >>= 1) p += __shfl_xor(p, off);
        if (c == 0) {
            float v2 = p;
            float zeta = 1.f / (sqrtf(1.f - v2) + 1e-8f);
            zkg[r * 4]     = zeta;
            zkg[r * 4 + 1] = (zeta - 1.f) / (v2 + 1e-9f);
            zkg[r * 4 + 2] = v2;
        }
    }
    __syncthreads();

    if (tid < 252) {
        int s = tid >> 2, p = tid & 3;
        const float* vr = &vvh[s * VSTR + p * 16];
        float sum = 0.f;
        #pragma unroll
        for (int j = 0; j < 16; j++) { float v = vr[j]; sum = fmaf(v, v, sum); }
        sum = qreduce(sum);
        if (p == 0) sch[s] = sqrtf(2.f / sum);
        const float* vr2 = &vvt[s * VSTR + p * 16];
        float sum2 = 0.f;
        #pragma unroll
        for (int j = 0; j < 16; j++) { float v = vr2[j]; sum2 = fmaf(v, v, sum2); }
        sum2 = qreduce(sum2);
        if (p == 0) sct[s] = sqrtf(2.f / sum2);
    }
    for (int i = tid; i < 1024; i += 512)
        if (pos[3 * i + 1] == r) { int s = atomicAdd(&bcnt, 1); if (s < 64) blist[s] = i; }
    __syncthreads();

    for (int idx = tid; idx < DM1 * 64; idx += 512) {
        int s = idx >> 6, j = idx & 63;
        vvh[s * VSTR + j] *= sch[s];
        vvt[s * VSTR + j] *= sct[s];
    }
    __syncthreads();

    int lane = tid & 63, wv = tid >> 6;   // wv 0..7
    int g = lane >> 4, c = lane & 15;     // group g (4/wave), lane-part c
    int cnt = bcnt < 64 ? bcnt : 64;
    float zeta_h = hcons[0], kz_h = hcons[1];

    int rounds = (cnt + 30) / 31; if (rounds < 1) rounds = 1;
    for (int rd = 0; rd < rounds; rd++) {
        int gslot = wv * 4 + g;                       // 0..31
        bool iswro = (rd == 0) && (gslot == 0);
        int eslot = rd * 31 + gslot - 1;              // entry index
        bool isent = (gslot > 0) && (eslot < cnt);
        int bb = isent ? blist[eslot] : 0;
        int u  = pos[3 * bb];
        const float* hrow = emb + (size_t)u * 64;

        f4 a = ((const f4*)hrow)[c];
        float an0 = __shfl(a[0], lane + 1);
        f4 y;
        y[0] = a[1]; y[1] = a[2]; y[2] = a[3];
        y[3] = (c == 15) ? 0.f : an0;
        if (!isent) y = (f4)0.f;
        float x0 = hrow[0];

        #pragma unroll 7
        for (int s = 0; s < 63; s++) {
            f4 vs = *(const f4*)(&vvh[s * VSTR + 4 * c]);
            float dot = red16(dot4(y, vs));
            y -= dot * vs;
        }

        f4 rh4 = ((const f4*)rovh_s)[c];
        f4 rt4 = ((const f4*)rovt_s)[c];
        float dot = red16(dot4(y, rh4));
        f4 th1 = y + (-zeta_h * x0) * rh4 + (kz_h * dot) * rh4;
        float th0 = zeta_h * x0 - zeta_h * dot;
        float nn = red16(dot4(th1, th1));
        float qq = red16(dot4(th1, rt4));
        if (isent && c == 0) {
            thcg[bb * 4]     = th0;
            thcg[bb * 4 + 1] = nn;
            thcg[bb * 4 + 2] = qq;
            thcg[bb * 4 + 3] = tanhf(bh[u]);
        }

        f4 z = isent ? th1 : (iswro ? rt4 : (f4)0.f);
        #pragma unroll 7
        for (int s = 62; s >= 0; s--) {
            f4 vs = *(const f4*)(&vvt[s * VSTR + 4 * c]);
            float d2 = red16(dot4(z, vs));
            z -= d2 * vs;
        }

        if (isent) {
            float* wo = wthg + bb * 64;
            if (c == 0) wo[0] = 0.f;
            #pragma unroll
            for (int k = 0; k < 4; k++) {
                int idx = 4 * c + k;
                if (idx < 63) wo[1 + idx] = z[k];
            }
        } else if (iswro) {
            float* wo = wrog + r * 64;
            if (c == 0) wo[0] = 0.f;
            #pragma unroll
            for (int k = 0; k < 4; k++) {
                int idx = 4 * c + k;
                if (idx < 63) wo[1 + idx] = z[k];
            }
        }
    }
}

// ---------------- K3 (exact r15 form): quad-cooperative gather, 1024 blocks,
// 256 threads, cc=4 (max per-thread loads in flight).
__global__ __launch_bounds__(256) void k3_score(
    const int* __restrict__ pos, const int* __restrict__ neg,
    const float* __restrict__ emb, const float* __restrict__ bt,
    const float* __restrict__ wrog, const float* __restrict__ wthg,
    const float* __restrict__ thcg, const float* __restrict__ zkg,
    float* __restrict__ out) {
    __shared__ __align__(16) float wro_s[64];
    __shared__ __align__(16) float wth_s[64];
    __shared__ float cst[7];

    int b = blockIdx.x, j = threadIdx.x;
    int r = pos[b * 3 + 1];
    int qslot = j >> 2, p = j & 3;

    if (j < 16)            ((f4*)wro_s)[j]      = ((const f4*)(wrog + r * 64))[j];
    else if (j < 32)       ((f4*)wth_s)[j - 16] = ((const f4*)(wthg + b * 64))[j - 16];
    else if (j == 32)      { cst[0] = zkg[r * 4]; cst[1] = zkg[r * 4 + 1]; cst[2] = zkg[r * 4 + 2]; }
    else if (j == 33)      { const float* tc = thcg + b * 4;
                             cst[3] = tc[0]; cst[4] = tc[1]; cst[5] = tc[2]; cst[6] = tc[3]; }
    __syncthreads();

    float zeta = cst[0], kk = cst[1], v2 = cst[2];
    float th0 = cst[3], nrm = cst[4], qd = cst[5], bhu = cst[6];
    const f4* wr4 = (const f4*)wro_s + p * 4;
    const f4* wt4 = (const f4*)wth_s + p * 4;

    #pragma unroll
    for (int cc = 0; cc < 4; cc++) {
        int cand = cc * 64 + qslot;
        int v = (cand == 0) ? pos[b * 3 + 2] : neg[b * 255 + cand - 1];
        const f4* tp = (const f4*)(emb + (size_t)v * 64) + p * 4;
        f4 t0 = tp[0], t1 = tp[1], t2 = tp[2], t3 = tp[3];
        float btv = bt[v];

        float x0 = qbcast0(t0[0]);                   // element 0 lives in lane p=0
        f4 a1 = t0 * wr4[0] + t1 * wr4[1] + t2 * wr4[2] + t3 * wr4[3];
        f4 a2 = t0 * wt4[0] + t1 * wt4[1] + t2 * wt4[2] + t3 * wt4[3];
        f4 a3 = t0 * t0 + t1 * t1 + t2 * t2 + t3 * t3;
        float s1 = qreduce((a1[0] + a1[1]) + (a1[2] + a1[3]));
        float s2 = qreduce((a2[0] + a2[1]) + (a2[2] + a2[3]));
        float s3 = qreduce((a3[0] + a3[1]) + (a3[2] + a3[3])) - x0 * x0;

        float A  = fmaf(kk, s1, -zeta * x0);
        float d0 = fmaf(zeta, x0 - s1, -th0);
        float m1 = s3 + nrm - 2.f * s2 + A * (2.f * (s1 - qd) + A * v2);
        float mkv = m1 - d0 * d0;
        if (p == 0) out[b * 256 + cand] = 0.85f - mkv + bhu + tanhf(btv);
    }
}

extern "C" void kernel_launch(void* const* d_in, const int* in_sizes, int n_in,
                              void* d_out, int out_size, void* d_ws, size_t ws_size,
                              hipStream_t stream) {
    const int*   pos = (const int*)d_in[0];
    const int*   neg = (const int*)d_in[1];
    const float* emb = (const float*)d_in[2];
    const float* bh  = (const float*)d_in[3];
    const float* bt  = (const float*)d_in[4];
    const float* rwh = (const float*)d_in[5];
    const float* bwh = (const float*)d_in[6];
    const float* rwt = (const float*)d_in[7];
    const float* bwt = (const float*)d_in[8];
    float* ws   = (float*)d_ws;
    float* wrog = ws + OFF_WRO;
    float* wthg = ws + OFF_WTH;
    float* thcg = ws + OFF_TC;
    float* zkg  = ws + OFF_ZK;
    float* out  = (float*)d_out;

    k_prep  <<<dim3(512),  dim3(512), 0, stream>>>(rwh, rwt, bwh, bwt, pos, emb,
                                                   bh, wrog, wthg, thcg, zkg);
    k3_score<<<dim3(1024), dim3(256), 0, stream>>>(pos, neg, emb, bt, wrog, wthg,
                                                   thcg, zkg, out);
}

// Round 19
// 38.614 us; speedup vs baseline: 1.1781x; 1.1016x over previous
//
#include <hip/hip_runtime.h>
#include <math.h>

#define DM1 63
#define VSTR 68            // LDS row stride for v-vectors

typedef float f4 __attribute__((ext_vector_type(4)));

// d_ws float offsets
#define OFF_WRO 0u                          // shifted W_t*ro: 512*64
#define SZ_WRO  (512u*64u)
#define OFF_WTH (OFF_WRO + SZ_WRO)          // shifted W_t*th1: 1024*64
#define SZ_WTH  (1024u*64u)
#define OFF_TC  (OFF_WTH + SZ_WTH)          // per-b consts {th0,nrm,q,bhu}: 1024*4
#define SZ_TC   (1024u*4u)
#define OFF_ZK  (OFF_TC + SZ_TC)            // per-r consts {zeta,kk,v2,-}: 512*4

__device__ __forceinline__ float qreduce(float d) {   // 4-lane quad sum
    int t = __builtin_amdgcn_mov_dpp(__float_as_int(d), 0xB1, 0xF, 0xF, true);
    d += __int_as_float(t);
    t = __builtin_amdgcn_mov_dpp(__float_as_int(d), 0x4E, 0xF, 0xF, true);
    d += __int_as_float(t);
    return d;
}

__device__ __forceinline__ float qbcast0(float x) {   // broadcast lane 4k -> quad
    return __int_as_float(__builtin_amdgcn_mov_dpp(__float_as_int(x), 0x00, 0xF, 0xF, true));
}

// 64-lane sum via DPP row_shr/row_bcast ladder; uniform result via readlane(63).
__device__ __forceinline__ float wred(float x) {
    float s = x;
#define ST(ctrl, rmask) s += __int_as_float(__builtin_amdgcn_update_dpp( \
        0, __float_as_int(s), ctrl, rmask, 0xF, true))
    ST(0x111, 0xF);   // row_shr:1
    ST(0x112, 0xF);   // row_shr:2
    ST(0x114, 0xF);   // row_shr:4
    ST(0x118, 0xF);   // row_shr:8
    ST(0x142, 0xA);   // row_bcast:15 -> rows 1,3
    ST(0x143, 0xC);   // row_bcast:31 -> rows 2,3
#undef ST
    return __int_as_float(__builtin_amdgcn_readlane(__float_as_int(s), 63));
}

// ---------------- K_prep (r15 form): one block per relation, 512 threads.
// gelu both sides into LDS, then matrix-vector Householder applications only.
__global__ __launch_bounds__(512) void k_prep(const float* __restrict__ rwh,
                                              const float* __restrict__ rwt,
                                              const float* __restrict__ bwh,
                                              const float* __restrict__ bwt,
                                              const int* __restrict__ pos,
                                              const float* __restrict__ emb,
                                              const float* __restrict__ bh,
                                              float* __restrict__ wrog,
                                              float* __restrict__ wthg,
                                              float* __restrict__ thcg,
                                              float* __restrict__ zkg) {
    int r = blockIdx.x;                  // 0..511
    __shared__ __align__(16) float vvh[DM1 * VSTR];
    __shared__ __align__(16) float vvt[DM1 * VSTR];
    __shared__ float sch[64], sct[64];
    __shared__ float rovh_s[64], rovt_s[64];
    __shared__ float hcons[2];           // zeta_h, kz_h
    __shared__ int blist[64];
    __shared__ int bcnt;
    int tid = threadIdx.x;
    if (tid == 0) bcnt = 0;

    const float* rwhr = rwh + (size_t)r * 3969;
    const float* rwtr = rwt + (size_t)r * 3969;
    for (int idx = tid; idx < 3969; idx += 512) {
        int s = idx / 63, j = idx - s * 63;
        float xh = rwhr[idx], xt = rwtr[idx];
        vvh[s * VSTR + j] = 0.5f * xh * (1.f + erff(xh * 0.70710678118654752f));
        vvt[s * VSTR + j] = 0.5f * xt * (1.f + erff(xt * 0.70710678118654752f));
    }
    if (tid < DM1) { vvh[tid * VSTR + 63] = 0.f; vvt[tid * VSTR + 63] = 0.f; }

    if (tid < 64) {
        int c = tid;
        float rov = (c < 63) ? tanhf(bwh[r * 63 + c]) * 0.015625f : 0.f;
        rovh_s[c] = rov;
        float p = rov * rov;
        #pragma unroll
        for (int off = 32; off; off >>= 1) p += __shfl_xor(p, off);
        if (c == 0) {
            float v2 = p;
            float zeta = 1.f / (sqrtf(1.f - v2) + 1e-8f);
            hcons[0] = zeta;
            hcons[1] = (zeta - 1.f) / (v2 + 1e-9f);
        }
    } else if (tid < 128) {
        int c = tid - 64;
        float rov = (c < 63) ? tanhf(bwt[r * 63 + c]) * 0.015625f : 0.f;
        rovt_s[c] = rov;
        float p = rov * rov;
        #pragma unroll
        for (int off = 32; off; off >>= 1) p += __shfl_xor(p, off);
        if (c == 0) {
            float v2 = p;
            float zeta = 1.f / (sqrtf(1.f - v2) + 1e-8f);
            zkg[r * 4]     = zeta;
            zkg[r * 4 + 1] = (zeta - 1.f) / (v2 + 1e-9f);
            zkg[r * 4 + 2] = v2;
        }
    }
    __syncthreads();

    if (tid < 252) {
        int s = tid >> 2, p = tid & 3;
        const float* vr = &vvh[s * VSTR + p * 16];
        float sum = 0.f;
        #pragma unroll
        for (int j = 0; j < 16; j++) { float v = vr[j]; sum = fmaf(v, v, sum); }
        sum = qreduce(sum);
        if (p == 0) sch[s] = sqrtf(2.f / sum);
        const float* vr2 = &vvt[s * VSTR + p * 16];
        float sum2 = 0.f;
        #pragma unroll
        for (int j = 0; j < 16; j++) { float v = vr2[j]; sum2 = fmaf(v, v, sum2); }
        sum2 = qreduce(sum2);
        if (p == 0) sct[s] = sqrtf(2.f / sum2);
    }
    for (int i = tid; i < 1024; i += 512)
        if (pos[3 * i + 1] == r) { int s = atomicAdd(&bcnt, 1); if (s < 64) blist[s] = i; }
    __syncthreads();

    for (int idx = tid; idx < DM1 * 64; idx += 512) {
        int s = idx >> 6, j = idx & 63;
        vvh[s * VSTR + j] *= sch[s];
        vvt[s * VSTR + j] *= sct[s];
    }
    __syncthreads();

    int lane = tid & 63, wv = tid >> 6;   // wv 0..7
    int cnt = bcnt < 64 ? bcnt : 64;
    float zeta_h = hcons[0], kz_h = hcons[1];

    if (wv == 0) {
        float y = rovt_s[lane];
        float vs = vvt[62 * VSTR + lane];
        #pragma unroll 7
        for (int s = 62; s >= 0; s--) {
            float vn = (s > 0) ? vvt[(s - 1) * VSTR + lane] : 0.f;
            float dot = wred(y * vs);
            y = fmaf(-dot, vs, y);
            vs = vn;
        }
        if (lane < 63) wrog[r * 64 + 1 + lane] = y;
        else           wrog[r * 64] = 0.f;
    } else {
        for (int e = wv - 1; e < cnt; e += 7) {
            int b = blist[e];
            int u = pos[3 * b];
            const float* hrow = emb + (size_t)u * 64;
            float x0 = hrow[0];
            float y = (lane < 63) ? hrow[1 + lane] : 0.f;
            float vs = vvh[0 * VSTR + lane];
            #pragma unroll 7
            for (int s = 0; s < 63; s++) {
                float vn = (s < 62) ? vvh[(s + 1) * VSTR + lane] : 0.f;
                float dot = wred(y * vs);
                y = fmaf(-dot, vs, y);
                vs = vn;
            }
            float rh = rovh_s[lane];
            float dot = wred(y * rh);
            float th1 = (lane < 63) ? fmaf(-zeta_h * x0, rh, y) + kz_h * rh * dot : 0.f;
            float th0 = zeta_h * x0 - zeta_h * dot;
            float nn = wred(th1 * th1);
            float qq = wred(th1 * rovt_s[lane]);
            if (lane == 0) {
                thcg[b * 4]     = th0;
                thcg[b * 4 + 1] = nn;
                thcg[b * 4 + 2] = qq;
                thcg[b * 4 + 3] = tanhf(bh[u]);
            }
            float z = th1;
            float ws2 = vvt[62 * VSTR + lane];
            #pragma unroll 7
            for (int s = 62; s >= 0; s--) {
                float wn = (s > 0) ? vvt[(s - 1) * VSTR + lane] : 0.f;
                float d2 = wred(z * ws2);
                z = fmaf(-d2, ws2, z);
                ws2 = wn;
            }
            if (lane < 63) wthg[b * 64 + 1 + lane] = z;
            else           wthg[b * 64] = 0.f;
        }
    }
}

// ---------------- K3: quad-cooperative gather scoring; ALL gather loads
// (indices, bt, t-rows) front-loaded above the barrier.
__global__ __launch_bounds__(256, 4) void k3_score(
    const int* __restrict__ pos, const int* __restrict__ neg,
    const float* __restrict__ emb, const float* __restrict__ bt,
    const float* __restrict__ wrog, const float* __restrict__ wthg,
    const float* __restrict__ thcg, const float* __restrict__ zkg,
    float* __restrict__ out) {
    __shared__ __align__(16) float wro_s[64];
    __shared__ __align__(16) float wth_s[64];
    __shared__ float cst[7];

    int b = blockIdx.x, j = threadIdx.x;
    int r = pos[b * 3 + 1];
    int qslot = j >> 2, p = j & 3;

    // ---- front-load all gathers (independent of LDS staging)
    int vv0 = (qslot == 0) ? pos[b * 3 + 2] : neg[b * 255 + qslot - 1];
    int vv1 = neg[b * 255 + 64 + qslot - 1];
    int vv2 = neg[b * 255 + 128 + qslot - 1];
    int vv3 = neg[b * 255 + 192 + qslot - 1];
    const f4* tp0 = (const f4*)(emb + (size_t)vv0 * 64) + p * 4;
    const f4* tp1 = (const f4*)(emb + (size_t)vv1 * 64) + p * 4;
    const f4* tp2 = (const f4*)(emb + (size_t)vv2 * 64) + p * 4;
    const f4* tp3 = (const f4*)(emb + (size_t)vv3 * 64) + p * 4;
    f4 t00 = tp0[0], t01 = tp0[1], t02 = tp0[2], t03 = tp0[3];
    f4 t10 = tp1[0], t11 = tp1[1], t12 = tp1[2], t13 = tp1[3];
    f4 t20 = tp2[0], t21 = tp2[1], t22 = tp2[2], t23 = tp2[3];
    f4 t30 = tp3[0], t31 = tp3[1], t32 = tp3[2], t33 = tp3[3];
    float bt0 = bt[vv0], bt1 = bt[vv1], bt2 = bt[vv2], bt3 = bt[vv3];

    // ---- stage per-block vectors/consts in LDS
    if (j < 16)            ((f4*)wro_s)[j]      = ((const f4*)(wrog + r * 64))[j];
    else if (j < 32)       ((f4*)wth_s)[j - 16] = ((const f4*)(wthg + b * 64))[j - 16];
    else if (j == 32)      { cst[0] = zkg[r * 4]; cst[1] = zkg[r * 4 + 1]; cst[2] = zkg[r * 4 + 2]; }
    else if (j == 33)      { const float* tc = thcg + b * 4;
                             cst[3] = tc[0]; cst[4] = tc[1]; cst[5] = tc[2]; cst[6] = tc[3]; }
    __syncthreads();

    float zeta = cst[0], kk = cst[1], v2 = cst[2];
    float th0 = cst[3], nrm = cst[4], qd = cst[5], bhu = cst[6];
    const f4* wr4p = (const f4*)wro_s + p * 4;
    const f4* wt4p = (const f4*)wth_s + p * 4;
    f4 wr0 = wr4p[0], wr1 = wr4p[1], wr2 = wr4p[2], wr3 = wr4p[3];
    f4 wt0 = wt4p[0], wt1 = wt4p[1], wt2 = wt4p[2], wt3 = wt4p[3];

#define SCORE(cc, T0, T1, T2, T3, BTV) do { \
    int cand = cc * 64 + qslot; \
    float x0 = qbcast0(T0[0]); \
    f4 a1 = T0 * wr0 + T1 * wr1 + T2 * wr2 + T3 * wr3; \
    f4 a2 = T0 * wt0 + T1 * wt1 + T2 * wt2 + T3 * wt3; \
    f4 a3 = T0 * T0 + T1 * T1 + T2 * T2 + T3 * T3; \
    float s1 = qreduce((a1[0] + a1[1]) + (a1[2] + a1[3])); \
    float s2 = qreduce((a2[0] + a2[1]) + (a2[2] + a2[3])); \
    float s3 = qreduce((a3[0] + a3[1]) + (a3[2] + a3[3])) - x0 * x0; \
    float A  = fmaf(kk, s1, -zeta * x0); \
    float d0 = fmaf(zeta, x0 - s1, -th0); \
    float m1 = s3 + nrm - 2.f * s2 + A * (2.f * (s1 - qd) + A * v2); \
    float mkv = m1 - d0 * d0; \
    if (p == 0) out[b * 256 + cand] = 0.85f - mkv + bhu + tanhf(BTV); \
} while (0)

    SCORE(0, t00, t01, t02, t03, bt0);
    SCORE(1, t10, t11, t12, t13, bt1);
    SCORE(2, t20, t21, t22, t23, bt2);
    SCORE(3, t30, t31, t32, t33, bt3);
#undef SCORE
}

extern "C" void kernel_launch(void* const* d_in, const int* in_sizes, int n_in,
                              void* d_out, int out_size, void* d_ws, size_t ws_size,
                              hipStream_t stream) {
    const int*   pos = (const int*)d_in[0];
    const int*   neg = (const int*)d_in[1];
    const float* emb = (const float*)d_in[2];
    const float* bh  = (const float*)d_in[3];
    const float* bt  = (const float*)d_in[4];
    const float* rwh = (const float*)d_in[5];
    const float* bwh = (const float*)d_in[6];
    const float* rwt = (const float*)d_in[7];
    const float* bwt = (const float*)d_in[8];
    float* ws   = (float*)d_ws;
    float* wrog = ws + OFF_WRO;
    float* wthg = ws + OFF_WTH;
    float* thcg = ws + OFF_TC;
    float* zkg  = ws + OFF_ZK;
    float* out  = (float*)d_out;

    k_prep  <<<dim3(512),  dim3(512), 0, stream>>>(rwh, rwt, bwh, bwt, pos, emb,
                                                   bh, wrog, wthg, thcg, zkg);
    k3_score<<<dim3(1024), dim3(256), 0, stream>>>(pos, neg, emb, bt, wrog, wthg,
                                                   thcg, zkg, out);
}